// Round 15
// baseline (33.145 us; speedup 1.0000x reference)
//
#include <hip/hip_runtime.h>

#define NP      8192
#define NCG     20
#define NC3     8000        // 20^3 unit cells over [0,20)^3
#define CELLCAP 8           // fixed u16 slots per cell (validated R5/R8/R12-R14)
#define NBLK    128         // build blocks
#define ROWS_PB 64          // rows per build block (1024 threads, 16 lanes/row)
#define SEG_PB  160         // fixed entry segment per block (7.7 sigma headroom)
#define ECAP    (NBLK*SEG_PB)   // 20480
#define CAP     16          // per-row candidate cap (pos fits 4 bits)
#define INF_U   0xFFFFFFFFu

// ---------- K1: one-pass-binning candidate build (128 blocks x 1024 threads) ----------
// R14 structure + per-entry payload cdp[e] = (d, (t.w - p.w)^2) so the matcher
// never touches pred/truec.
__global__ __launch_bounds__(1024)
void build_cands(const float4* __restrict__ pred,
                 const float4* __restrict__ truec,
                 unsigned int* __restrict__ ocg,     // row -> (occ<<31)|(start<<8)|n
                 unsigned short* __restrict__ Eg,    // ECAP entry cols (sorted per row)
                 float2* __restrict__ cdp) {         // ECAP entry payloads (d, dp^2)
    __shared__ unsigned short slot[NC3 * CELLCAP];     // 128000 B
    __shared__ unsigned int cc[NC3 / 2];               // 16000 B (u16 counts, 2/u32)
    __shared__ unsigned long long skey[ROWS_PB][CAP];  // 8192 B
    __shared__ int scnt[ROWS_PB];
    __shared__ int sst[ROWS_PB];
    int tid = threadIdx.x;
    int g = tid >> 4, l = tid & 15;                    // 16 lanes per row

    for (int c = tid; c < NC3 / 2; c += 1024) cc[c] = 0;
    if (l == 0) scnt[g] = 0;
    __syncthreads();

    // one-pass bin: count + slot write together
    #pragma unroll
    for (int k = 0; k < 8; ++k) {
        int i = k * 1024 + tid;
        float4 p = pred[i];
        if (p.w >= 0.5f) {
            int cx = min((int)p.x, NCG - 1);
            int cy = min((int)p.y, NCG - 1);
            int cz = min((int)p.z, NCG - 1);
            int cell = (cz * NCG + cy) * NCG + cx;
            int sh = (cell & 1) * 16;
            unsigned int old = atomicAdd(&cc[cell >> 1], 1u << sh);
            int rk = (int)((old >> sh) & 0xFFFFu);
            if (rk < CELLCAP) slot[cell * CELLCAP + rk] = (unsigned short)i;
        }
    }
    __syncthreads();

    // search: 27-cell neighborhood; slots in LDS, pred[j] from L2
    int row = blockIdx.x * ROWS_PB + g;
    float4 t = truec[row];
    if (t.w >= 0.5f) {
        int cx = min((int)t.x, NCG - 1);
        int cy = min((int)t.y, NCG - 1);
        int cz = min((int)t.z, NCG - 1);
        for (int ci = l; ci < 27; ci += 16) {
            int zz = cz + ci / 9 - 1;
            int yy = cy + (ci / 3) % 3 - 1;
            int xx = cx + ci % 3 - 1;
            if (zz < 0 || zz >= NCG || yy < 0 || yy >= NCG || xx < 0 || xx >= NCG)
                continue;
            int cell = (zz * NCG + yy) * NCG + xx;
            int cnt = (int)((cc[cell >> 1] >> ((cell & 1) * 16)) & 0xFFFFu);
            if (cnt > CELLCAP) cnt = CELLCAP;
            int sbase = cell * CELLCAP;
            for (int k = 0; k < cnt; ++k) {
                int j = slot[sbase + k];
                float4 pp = pred[j];
                float dx = t.x - pp.x, dy = t.y - pp.y, dz = t.z - pp.z;
                float d = sqrtf(dx * dx + dy * dy + dz * dz);
                if (d <= 1.0f) {
                    int a = atomicAdd(&scnt[g], 1);
                    if (a < CAP)
                        skey[g][a] = ((unsigned long long)__float_as_uint(d) << 32)
                                     | (unsigned int)j;
                }
            }
        }
    }
    __syncthreads();
    if (l == 0) {
        int n = min(scnt[g], CAP);
        for (int a = 1; a < n; ++a) {            // (d asc, j asc) = argmin tie-break
            unsigned long long kv = skey[g][a];
            int b = a - 1;
            while (b >= 0 && skey[g][b] > kv) { skey[g][b + 1] = skey[g][b]; --b; }
            skey[g][b + 1] = kv;
        }
        scnt[g] = n;
    }
    __syncthreads();
    // allocate within the block's FIXED segment (single-wave scan of 64 counts)
    if (tid < ROWS_PB) {
        int n = scnt[tid];
        int inc = n;
        #pragma unroll
        for (int o = 1; o < 64; o <<= 1) {
            int u = __shfl_up(inc, o);
            if (tid >= o) inc += u;
        }
        int st = inc - n;
        int nn = n;
        if (st >= SEG_PB) nn = 0;                // ~7.7 sigma guard
        else if (st + nn > SEG_PB) nn = SEG_PB - st;
        sst[tid] = st;
        scnt[tid] = nn;
        int r = blockIdx.x * ROWS_PB + tid;
        unsigned int occ2 = (truec[r].w >= 0.5f) ? 1u : 0u;
        unsigned int start = (nn > 0) ? (unsigned int)(blockIdx.x * SEG_PB + st) : 0u;
        ocg[r] = (occ2 << 31) | (start << 8) | (unsigned int)nn;
    }
    __syncthreads();
    {
        int st = blockIdx.x * SEG_PB + sst[g];
        int nn = scnt[g];
        for (int k = l; k < nn; k += 16) {
            unsigned long long kv = skey[g][k];
            int j = (int)(kv & 0x1FFFu);
            Eg[st + k] = (unsigned short)j;
            float d = __uint_as_float((unsigned int)(kv >> 32));
            float dp = t.w - pred[j].w;
            cdp[st + k] = make_float2(d, dp * dp);
        }
    }
}

// ---------- K2: LDS Gale-Shapley, 4-slot chain pool with refill ----------
// H[col] = (row<<4)|pos under LDS atomicMin (monotone-decreasing). Any
// scheduling reaches the same fixed point == the reference's serial greedy
// scan (validated absmax=0.0, rounds 1-14). Reduction reads only cdp.
__global__ __launch_bounds__(1024)
void match_reduce(const unsigned int* __restrict__ ocg,
                  const unsigned short* __restrict__ Eg,
                  const float2* __restrict__ cdp,
                  float* __restrict__ out) {
    __shared__ unsigned short E[ECAP];    // 40KB
    __shared__ unsigned int ocs[NP];      // 32KB packed row descriptors
    __shared__ unsigned int Hs[NP];       // 32KB
    __shared__ float redf[2][16];
    __shared__ int redi[2][16];
    int tid = threadIdx.x;
    #pragma unroll
    for (int x = tid; x < ECAP / 8; x += 1024)
        ((uint4*)E)[x] = ((const uint4*)Eg)[x];
    #pragma unroll
    for (int x = tid; x < NP / 4; x += 1024)
        ((uint4*)ocs)[x] = ((const uint4*)ocg)[x];
    #pragma unroll
    for (int x = tid; x < NP / 4; x += 1024)
        ((uint4*)Hs)[x] = make_uint4(INF_U, INF_U, INF_U, INF_U);
    __syncthreads();

    int mynocc = 0;
    int nextk = 0;
    bool a0 = false, a1 = false, a2 = false, a3 = false;
    int r0 = 0, p0 = 0, n0 = 0, e0 = 0;
    int r1 = 0, p1 = 0, n1 = 0, e1 = 0;
    int r2 = 0, p2 = 0, n2 = 0, e2 = 0;
    int r3 = 0, p3 = 0, n3 = 0, e3 = 0;

#define REFILL(A, R, P, N, EE)                                          \
    while (!A && nextk < 8) {                                           \
        int row_ = nextk * 1024 + tid; ++nextk;                         \
        unsigned int oc_ = ocs[row_];                                   \
        mynocc += (int)(oc_ >> 31);                                     \
        int nn_ = (int)(oc_ & 0xFFu);                                   \
        if (nn_) { A = true; R = row_; P = 0; N = nn_;                  \
                   EE = (int)((oc_ >> 8) & 0x7FFFFFu); }                \
    }
#define RESOLVE(A, R, P, N, EE, OLD)                                    \
    if (A) {                                                            \
        unsigned int key_ = ((unsigned int)R << 4) | (unsigned int)P;   \
        if (OLD > key_) {                                               \
            if (OLD == INF_U) A = false;                                \
            else {                                                      \
                R = (int)(OLD >> 4); P = (int)(OLD & 15u) + 1;          \
                unsigned int oc_ = ocs[R];                              \
                N = (int)(oc_ & 0xFFu);                                 \
                if (P >= N) A = false;                                  \
                else EE = (int)((oc_ >> 8) & 0x7FFFFFu) + P;            \
            }                                                           \
        } else {                                                        \
            if (++P >= N) A = false; else ++EE;                         \
        }                                                               \
    }

    REFILL(a0, r0, p0, n0, e0)
    REFILL(a1, r1, p1, n1, e1)
    REFILL(a2, r2, p2, n2, e2)
    REFILL(a3, r3, p3, n3, e3)
    while (a0 || a1 || a2 || a3) {
        unsigned int c0 = 0, c1 = 0, c2 = 0, c3 = 0;
        if (a0) c0 = E[e0];
        if (a1) c1 = E[e1];
        if (a2) c2 = E[e2];
        if (a3) c3 = E[e3];
        unsigned int o0 = 0, o1 = 0, o2 = 0, o3 = 0;
        if (a0) o0 = atomicMin(&Hs[c0], ((unsigned int)r0 << 4) | (unsigned int)p0);
        if (a1) o1 = atomicMin(&Hs[c1], ((unsigned int)r1 << 4) | (unsigned int)p1);
        if (a2) o2 = atomicMin(&Hs[c2], ((unsigned int)r2 << 4) | (unsigned int)p2);
        if (a3) o3 = atomicMin(&Hs[c3], ((unsigned int)r3 << 4) | (unsigned int)p3);
        RESOLVE(a0, r0, p0, n0, e0, o0) REFILL(a0, r0, p0, n0, e0)
        RESOLVE(a1, r1, p1, n1, e1, o1) REFILL(a1, r1, p1, n1, e1)
        RESOLVE(a2, r2, p2, n2, e2, o2) REFILL(a2, r2, p2, n2, e2)
        RESOLVE(a3, r3, p3, n3, e3, o3) REFILL(a3, r3, p3, n3, e3)
    }
#undef REFILL
#undef RESOLVE
    __syncthreads();

    // matched-only reduction over cols (fixed order -> deterministic); 8B/match
    float sdist = 0.f, sprob = 0.f;
    int nm = 0;
    for (int j = tid; j < NP; j += 1024) {
        unsigned int h = Hs[j];
        if (h != INF_U) {
            int r = (int)(h >> 4);
            int p = (int)(h & 15u);
            unsigned int oc = ocs[r];
            int e = (int)((oc >> 8) & 0x7FFFFFu) + p;
            float2 v = cdp[e];
            sdist += v.x;
            sprob += v.y;
            ++nm;
        }
    }
    for (int o = 32; o; o >>= 1) {
        sdist += __shfl_down(sdist, o);
        sprob += __shfl_down(sprob, o);
        nm     += __shfl_down(nm, o);
        mynocc += __shfl_down(mynocc, o);
    }
    int wave = tid >> 6, lane = tid & 63;
    if (lane == 0) {
        redf[0][wave] = sdist; redf[1][wave] = sprob;
        redi[0][wave] = nm;    redi[1][wave] = mynocc;
    }
    __syncthreads();
    if (tid == 0) {
        float S = 0.f, P = 0.f; int NM = 0, NO = 0;
        for (int w = 0; w < 16; ++w) {
            S += redf[0][w]; P += redf[1][w];
            NM += redi[0][w]; NO += redi[1][w];
        }
        float nmf = (float)NM;
        float unm = (float)NO - nmf;
        out[0] = (S / nmf + 10.0f * unm) + (P / nmf + unm);
    }
}

extern "C" void kernel_launch(void* const* d_in, const int* in_sizes, int n_in,
                              void* d_out, int out_size, void* d_ws, size_t ws_size,
                              hipStream_t stream) {
    const float4* pred  = (const float4*)d_in[0];
    const float4* truec = (const float4*)d_in[1];
    float* out = (float*)d_out;

    unsigned int* ocg   = (unsigned int*)d_ws;                   // NP u32   (32KB)
    unsigned short* Eg  = (unsigned short*)(ocg + NP);           // ECAP u16 (40KB)
    float2* cdp         = (float2*)((char*)d_ws + 73728);        // ECAP f2  (160KB)

    build_cands <<<NBLK, 1024, 0, stream>>>(pred, truec, ocg, Eg, cdp);
    match_reduce<<<1,    1024, 0, stream>>>(ocg, Eg, cdp, out);
}

// Round 17
// 28.718 us; speedup vs baseline: 1.1542x; 1.1542x over previous
//
#include <hip/hip_runtime.h>

#define NP      8192
#define NCG     20
#define NC3     8000        // 20^3 unit cells over [0,20)^3
#define CELLCAP 8           // fixed u16 slots per cell (validated R5/R8/R12-R14)
#define NBLK    128         // build blocks
#define ROWS_PB 64          // rows per build block (1024 threads, 16 lanes/row)
#define SEG_PB  160         // fixed entry segment per block (7.7 sigma headroom)
#define ECAP    (NBLK*SEG_PB)   // 20480
#define CAP     16          // per-row candidate cap (pos fits 4 bits)
#define INF_U   0xFFFFFFFFu

// ---------- K1: one-pass-binning candidate build (128 blocks x 1024 threads) ----------
// oc[r] = (occupied<<31) | (entry_start<<8) | count.
__global__ __launch_bounds__(1024)
void build_cands(const float4* __restrict__ pred,
                 const float4* __restrict__ truec,
                 unsigned int* __restrict__ ocg,     // row -> packed descriptor
                 unsigned short* __restrict__ Eg) {  // ECAP entry cols (sorted per row)
    __shared__ unsigned short slot[NC3 * CELLCAP];     // 128000 B
    __shared__ unsigned int cc[NC3 / 2];               // 16000 B (u16 counts, 2/u32)
    __shared__ unsigned long long skey[ROWS_PB][CAP];  // 8192 B
    __shared__ int scnt[ROWS_PB];
    __shared__ int sst[ROWS_PB];
    int tid = threadIdx.x;
    int g = tid >> 4, l = tid & 15;                    // 16 lanes per row

    for (int c = tid; c < NC3 / 2; c += 1024) cc[c] = 0;
    if (l == 0) scnt[g] = 0;
    __syncthreads();

    // one-pass bin: count + slot write together
    #pragma unroll
    for (int k = 0; k < 8; ++k) {
        int i = k * 1024 + tid;
        float4 p = pred[i];
        if (p.w >= 0.5f) {
            int cx = min((int)p.x, NCG - 1);
            int cy = min((int)p.y, NCG - 1);
            int cz = min((int)p.z, NCG - 1);
            int cell = (cz * NCG + cy) * NCG + cx;
            int sh = (cell & 1) * 16;
            unsigned int old = atomicAdd(&cc[cell >> 1], 1u << sh);
            int rk = (int)((old >> sh) & 0xFFFFu);
            if (rk < CELLCAP) slot[cell * CELLCAP + rk] = (unsigned short)i;
        }
    }
    __syncthreads();

    // search: 27-cell neighborhood; slots in LDS, pred[j] from L2
    int row = blockIdx.x * ROWS_PB + g;
    float4 t = truec[row];
    if (t.w >= 0.5f) {
        int cx = min((int)t.x, NCG - 1);
        int cy = min((int)t.y, NCG - 1);
        int cz = min((int)t.z, NCG - 1);
        for (int ci = l; ci < 27; ci += 16) {
            int zz = cz + ci / 9 - 1;
            int yy = cy + (ci / 3) % 3 - 1;
            int xx = cx + ci % 3 - 1;
            if (zz < 0 || zz >= NCG || yy < 0 || yy >= NCG || xx < 0 || xx >= NCG)
                continue;
            int cell = (zz * NCG + yy) * NCG + xx;
            int cnt = (int)((cc[cell >> 1] >> ((cell & 1) * 16)) & 0xFFFFu);
            if (cnt > CELLCAP) cnt = CELLCAP;
            int sbase = cell * CELLCAP;
            for (int k = 0; k < cnt; ++k) {
                int j = slot[sbase + k];
                float4 pp = pred[j];
                float dx = t.x - pp.x, dy = t.y - pp.y, dz = t.z - pp.z;
                float d = sqrtf(dx * dx + dy * dy + dz * dz);
                if (d <= 1.0f) {
                    int a = atomicAdd(&scnt[g], 1);
                    if (a < CAP)
                        skey[g][a] = ((unsigned long long)__float_as_uint(d) << 32)
                                     | (unsigned int)j;
                }
            }
        }
    }
    __syncthreads();
    if (l == 0) {
        int n = min(scnt[g], CAP);
        for (int a = 1; a < n; ++a) {            // (d asc, j asc) = argmin tie-break
            unsigned long long kv = skey[g][a];
            int b = a - 1;
            while (b >= 0 && skey[g][b] > kv) { skey[g][b + 1] = skey[g][b]; --b; }
            skey[g][b + 1] = kv;
        }
        scnt[g] = n;
    }
    __syncthreads();
    // allocate within the block's FIXED segment (single-wave scan of 64 counts)
    if (tid < ROWS_PB) {
        int n = scnt[tid];
        int inc = n;
        #pragma unroll
        for (int o = 1; o < 64; o <<= 1) {
            int u = __shfl_up(inc, o);
            if (tid >= o) inc += u;
        }
        int st = inc - n;
        int nn = n;
        if (st >= SEG_PB) nn = 0;                // ~7.7 sigma guard
        else if (st + nn > SEG_PB) nn = SEG_PB - st;
        sst[tid] = st;
        scnt[tid] = nn;
        int r = blockIdx.x * ROWS_PB + tid;
        unsigned int occ2 = (truec[r].w >= 0.5f) ? 1u : 0u;
        unsigned int start = (nn > 0) ? (unsigned int)(blockIdx.x * SEG_PB + st) : 0u;
        ocg[r] = (occ2 << 31) | (start << 8) | (unsigned int)nn;
    }
    __syncthreads();
    {
        int st = blockIdx.x * SEG_PB + sst[g];
        int nn = scnt[g];
        for (int k = l; k < nn; k += 16)
            Eg[st + k] = (unsigned short)(skey[g][k] & 0x1FFFu);
    }
}

// ---------- K2: LDS chain-following Gale-Shapley, 2 interleaved chains/thread ----------
// H[col] = (row<<4)|pos under LDS atomicMin (monotone-decreasing). Direct
// atomicMin (no pre-check): old > key => won, else advance. Fixed point ==
// the reference's serial greedy scan (validated absmax=0.0, rounds 1-15).
__global__ __launch_bounds__(1024)
void match_reduce(const float4* __restrict__ pred,
                  const float4* __restrict__ truec,
                  const unsigned int* __restrict__ ocg,
                  const unsigned short* __restrict__ Eg,
                  float* __restrict__ out) {
    __shared__ unsigned short E[ECAP];    // 40KB
    __shared__ unsigned int ocs[NP];      // 32KB packed row descriptors
    __shared__ unsigned int Hs[NP];       // 32KB
    __shared__ float redf[2][16];
    __shared__ int redi[2][16];
    int tid = threadIdx.x;
    #pragma unroll
    for (int x = tid; x < ECAP / 8; x += 1024)
        ((uint4*)E)[x] = ((const uint4*)Eg)[x];
    #pragma unroll
    for (int x = tid; x < NP / 4; x += 1024)
        ((uint4*)ocs)[x] = ((const uint4*)ocg)[x];
    #pragma unroll
    for (int x = tid; x < NP / 4; x += 1024)
        ((uint4*)Hs)[x] = make_uint4(INF_U, INF_U, INF_U, INF_U);
    __syncthreads();

    int mynocc = 0;
    #pragma unroll
    for (int base = 0; base < NP; base += 2048) {
        int rA = base + tid, rB = base + 1024 + tid;
        unsigned int ocA = ocs[rA], ocB = ocs[rB];
        mynocc += (int)(ocA >> 31) + (int)(ocB >> 31);
        int nA = (int)(ocA & 0xFFu), nB = (int)(ocB & 0xFFu);
        int rAc = rA, rBc = rB;
        int pA = 0, pB = 0;
        int eA = (int)((ocA >> 8) & 0x7FFFFFu);
        int eB = (int)((ocB >> 8) & 0x7FFFFFu);
        bool aA = (nA > 0), aB = (nB > 0);
        while (aA || aB) {
            unsigned int colA = 0, colB = 0;
            if (aA) colA = E[eA];
            if (aB) colB = E[eB];
            unsigned int keyA = ((unsigned int)rAc << 4) | (unsigned int)pA;
            unsigned int keyB = ((unsigned int)rBc << 4) | (unsigned int)pB;
            unsigned int oldA = 0, oldB = 0;
            if (aA) oldA = atomicMin(&Hs[colA], keyA);
            if (aB) oldB = atomicMin(&Hs[colB], keyB);
            if (aA) {
                if (oldA > keyA) {
                    if (oldA == INF_U) aA = false;   // claimed free col
                    else {                           // displaced old holder: continue it
                        rAc = (int)(oldA >> 4);
                        pA = (int)(oldA & 15u) + 1;
                        unsigned int oc = ocs[rAc];
                        nA = (int)(oc & 0xFFu);
                        if (pA >= nA) aA = false;
                        else eA = (int)((oc >> 8) & 0x7FFFFFu) + pA;
                    }
                } else {                             // better row holds it: advance
                    if (++pA >= nA) aA = false;
                    else ++eA;
                }
            }
            if (aB) {
                if (oldB > keyB) {
                    if (oldB == INF_U) aB = false;
                    else {
                        rBc = (int)(oldB >> 4);
                        pB = (int)(oldB & 15u) + 1;
                        unsigned int oc = ocs[rBc];
                        nB = (int)(oc & 0xFFu);
                        if (pB >= nB) aB = false;
                        else eB = (int)((oc >> 8) & 0x7FFFFFu) + pB;
                    }
                } else {
                    if (++pB >= nB) aB = false;
                    else ++eB;
                }
            }
        }
    }
    __syncthreads();

    // matched-only reduction (fixed order -> deterministic)
    float sdist = 0.f, sprob = 0.f;
    int nm = 0;
    for (int j = tid; j < NP; j += 1024) {
        unsigned int h = Hs[j];
        if (h != INF_U) {
            int r = (int)(h >> 4);
            float4 tt = truec[r];
            float4 pp = pred[j];
            float dx = tt.x - pp.x, dy = tt.y - pp.y, dz = tt.z - pp.z;
            sdist += sqrtf(dx * dx + dy * dy + dz * dz);
            float dp = tt.w - pp.w;
            sprob += dp * dp;
            ++nm;
        }
    }
    for (int o = 32; o; o >>= 1) {
        sdist += __shfl_down(sdist, o);
        sprob += __shfl_down(sprob, o);
        nm     += __shfl_down(nm, o);
        mynocc += __shfl_down(mynocc, o);
    }
    int wave = tid >> 6, lane = tid & 63;
    if (lane == 0) {
        redf[0][wave] = sdist; redf[1][wave] = sprob;
        redi[0][wave] = nm;    redi[1][wave] = mynocc;
    }
    __syncthreads();
    if (tid == 0) {
        float S = 0.f, P = 0.f; int NM = 0, NO = 0;
        for (int w = 0; w < 16; ++w) {
            S += redf[0][w]; P += redf[1][w];
            NM += redi[0][w]; NO += redi[1][w];
        }
        float nmf = (float)NM;
        float unm = (float)NO - nmf;
        out[0] = (S / nmf + 10.0f * unm) + (P / nmf + unm);
    }
}

extern "C" void kernel_launch(void* const* d_in, const int* in_sizes, int n_in,
                              void* d_out, int out_size, void* d_ws, size_t ws_size,
                              hipStream_t stream) {
    const float4* pred  = (const float4*)d_in[0];
    const float4* truec = (const float4*)d_in[1];
    float* out = (float*)d_out;

    unsigned int* ocg   = (unsigned int*)d_ws;          // NP u32 (32KB)
    unsigned short* Eg  = (unsigned short*)(ocg + NP);  // ECAP u16 (40KB)

    build_cands <<<NBLK, 1024, 0, stream>>>(pred, truec, ocg, Eg);
    match_reduce<<<1,    1024, 0, stream>>>(pred, truec, ocg, Eg, out);
}